// Round 4
// baseline (1581.921 us; speedup 1.0000x reference)
//
#include <hip/hip_runtime.h>

#define F 3
#define V 512
#define D 8192
#define B 64
#define ITERS 10
#define NBLK 384
#define SIMN (F * B * V)

typedef __bf16 bf16_t;
typedef __bf16 bf16x8 __attribute__((ext_vector_type(8)));
typedef __bf16 bf16x4 __attribute__((ext_vector_type(4)));
typedef float f32x4 __attribute__((ext_vector_type(4)));

// ---------------------------------------------------------------------------
// grid barrier: device-scope acq/rel atomics; safe because all NBLK blocks
// are co-resident by capacity (384 blocks, 2+ blocks/CU guaranteed by
// __launch_bounds__(256,2) + 34.8 KB LDS -> >=512 capacity).
// ---------------------------------------------------------------------------
__device__ inline void gridbar(int* cnt, int* gen) {
  __syncthreads();
  if (threadIdx.x == 0) {
    int g = __hip_atomic_load(gen, __ATOMIC_RELAXED, __HIP_MEMORY_SCOPE_AGENT);
    int old = __hip_atomic_fetch_add(cnt, 1, __ATOMIC_ACQ_REL, __HIP_MEMORY_SCOPE_AGENT);
    if (old == NBLK - 1) {
      __hip_atomic_store(cnt, 0, __ATOMIC_RELAXED, __HIP_MEMORY_SCOPE_AGENT);
      __hip_atomic_fetch_add(gen, 1, __ATOMIC_ACQ_REL, __HIP_MEMORY_SCOPE_AGENT);
    } else {
      while (__hip_atomic_load(gen, __ATOMIC_ACQUIRE, __HIP_MEMORY_SCOPE_AGENT) == g)
        __builtin_amdgcn_s_sleep(2);
    }
  }
  __syncthreads();
}

// ---------------------------------------------------------------------------
// init: est0 = bf16(init_estimates); zero sim ping-pong, flags, barrier state
// ---------------------------------------------------------------------------
__global__ void k_init_small(const float* __restrict__ ie, bf16_t* __restrict__ est0,
                             float* __restrict__ simR, int* __restrict__ anydiff,
                             int* __restrict__ barst) {
  long tid = (long)blockIdx.x * blockDim.x + threadIdx.x;
  long NT  = (long)gridDim.x * blockDim.x;
  for (long i = tid * 4; i < (long)B * F * D; i += NT * 4) {
    f32x4 x = *(const f32x4*)(ie + i);
    bf16x4 y;
    y[0] = (bf16_t)x[0]; y[1] = (bf16_t)x[1]; y[2] = (bf16_t)x[2]; y[3] = (bf16_t)x[3];
    *(bf16x4*)(est0 + i) = y;
  }
  f32x4 z = {0.f, 0.f, 0.f, 0.f};
  for (long i = tid * 4; i < (long)2 * SIMN; i += NT * 4)
    *(f32x4*)(simR + i) = z;
  if (tid < 16) anydiff[tid] = 0;
  if (tid < 8)  barst[tid] = 0;
}

// ---------------------------------------------------------------------------
// init: codebooks (fp32, read once) -> Cb bf16 [f][v][d] and CbT bf16 [f][d][v]
// ---------------------------------------------------------------------------
__global__ __launch_bounds__(256) void k_init_cb(const float* __restrict__ Csrc,
                                                 bf16_t* __restrict__ Cb,
                                                 bf16_t* __restrict__ CbT) {
  int f = blockIdx.z, vt = blockIdx.y, dt = blockIdx.x;
  __shared__ bf16_t tile[64 * 65];
  int t = threadIdx.x;
  int v0 = vt * 64, d0 = dt * 64;
#pragma unroll
  for (int p = 0; p < 16; ++p) {
    int q = t + 256 * p;
    int i = q >> 6, j = q & 63;
    bf16_t x = (bf16_t)Csrc[((long)(f * V + v0 + i)) * D + d0 + j];
    tile[i * 65 + j] = x;
    Cb[((long)(f * V + v0 + i)) * D + d0 + j] = x;
  }
  __syncthreads();
#pragma unroll
  for (int p = 0; p < 16; ++p) {
    int q = t + 256 * p;
    int jj = q >> 6, ii = q & 63;
    CbT[((long)f * D + d0 + jj) * V + v0 + ii] = tile[ii * 65 + jj];
  }
}

// ---------------------------------------------------------------------------
// fused resonator loop: 10x (sim -> bar -> upd -> bar -> uniform break),
// then final projection -> bar -> argmax + count. One launch.
// All arithmetic exact (integer values; fp32 accum < 2^24; 256*h+l split).
// ---------------------------------------------------------------------------
__global__ __launch_bounds__(256, 2) void k_fused(const float* __restrict__ inputs,
                                                  const bf16_t* __restrict__ Cb,
                                                  const bf16_t* __restrict__ CbT,
                                                  bf16_t* __restrict__ est0,
                                                  bf16_t* __restrict__ est1,
                                                  float* __restrict__ simR,
                                                  int* __restrict__ anydiff,
                                                  int* __restrict__ barst,
                                                  int* __restrict__ out) {
  __shared__ __attribute__((aligned(16))) bf16_t lds[2 * 64 * 136];  // 34.8 KB
  bf16_t* lA  = lds;            // sim: A tile     | upd: hi plane
  bf16_t* lA2 = lds + 64 * 136; //                  | upd: lo plane

  int* cnt = barst;
  int* gen = barst + 4;

  const int bid = blockIdx.x;
  const int t = threadIdx.x;
  const int lane = t & 63, w = t >> 6;
  const int lm = lane & 15, quad = lane >> 4;

  // block roles
  const int fS = bid >> 7;            // sim: f 0..2
  const int rS = bid & 127;
  const int vtS = rS >> 4;            // 0..7   -> v0 = vtS*64
  const int ksS = rS & 15;            // 0..15  -> dbase = ksS*512
  const int fU = bid >> 7;            // upd: f 0..2
  const int dtU = bid & 127;          // 0..127 -> d0 = dtU*64

  int done_at = ITERS;

  for (int j = 0; j < ITERS; ++j) {
    // ---------------- sim phase: simR[j&1] += newest . Cb -----------------
    {
      const bf16_t* est = (j & 1) ? est1 : est0;
      float* sim = simR + (j & 1) * SIMN;
      const int f1 = (fS + 1) % 3, f2 = (fS + 2) % 3;
      const int v0 = vtS * 64;
      const int dbase = ksS * 512;
      const bf16_t* bp = Cb + ((long)(fS * V + v0 + w * 16 + lm)) * D + dbase;

      f32x4 zero = {0.f, 0.f, 0.f, 0.f};
      f32x4 acc[4];
#pragma unroll
      for (int mt = 0; mt < 4; ++mt) acc[mt] = zero;

      for (int c = 0; c < 4; ++c) {
        const int d0c = dbase + c * 128;
        __syncthreads();
#pragma unroll
        for (int p = 0; p < 4; ++p) {
          int q = t + 256 * p;
          int b = q >> 4, dd = (q & 15) * 8;
          const float* ip = inputs + (long)b * D + d0c + dd;
          f32x4 x0 = *(const f32x4*)ip;
          f32x4 x1 = *(const f32x4*)(ip + 4);
          bf16x8 e1 = *(const bf16x8*)(est + ((long)b * F + f1) * D + d0c + dd);
          bf16x8 e2 = *(const bf16x8*)(est + ((long)b * F + f2) * D + d0c + dd);
          bf16x8 o;
#pragma unroll
          for (int i = 0; i < 4; ++i) {
            o[i]     = (bf16_t)(x0[i] * (float)e1[i]     * (float)e2[i]);
            o[i + 4] = (bf16_t)(x1[i] * (float)e1[i + 4] * (float)e2[i + 4]);
          }
          *(bf16x8*)&lA[b * 136 + dd] = o;
        }
        __syncthreads();
#pragma unroll
        for (int ks2 = 0; ks2 < 4; ++ks2) {
          const int kb = ks2 * 32 + quad * 8;
          bf16x8 bfrag = *(const bf16x8*)(bp + c * 128 + kb);
#pragma unroll
          for (int mt = 0; mt < 4; ++mt) {
            bf16x8 afrag = *(const bf16x8*)&lA[(mt * 16 + lm) * 136 + kb];
            acc[mt] = __builtin_amdgcn_mfma_f32_16x16x32_bf16(afrag, bfrag, acc[mt], 0, 0, 0);
          }
        }
      }
      const int v = v0 + w * 16 + lm;
#pragma unroll
      for (int mt = 0; mt < 4; ++mt)
#pragma unroll
        for (int r = 0; r < 4; ++r) {
          int b = mt * 16 + quad * 4 + r;
          atomicAdd(&sim[(fS * B + b) * V + v], acc[mt][r]);
        }
    }
    gridbar(cnt, gen);

    // ---------------- upd phase: est' = sign(sim . CbT) -------------------
    {
      const bf16_t* estIn = (j & 1) ? est1 : est0;
      bf16_t* estOut = (j & 1) ? est0 : est1;
      const float* sim = simR + (j & 1) * SIMN + fU * (B * V);
      const int d0 = dtU * 64;
      const bf16_t* bp = CbT + ((long)fU * D + d0 + w * 16 + lm) * V;

      f32x4 zero = {0.f, 0.f, 0.f, 0.f};
      f32x4 accH[4], accL[4];
#pragma unroll
      for (int mt = 0; mt < 4; ++mt) { accH[mt] = zero; accL[mt] = zero; }

      for (int c = 0; c < 4; ++c) {
        const int vb = c * 128;
        __syncthreads();
#pragma unroll
        for (int p = 0; p < 4; ++p) {
          int q = t + 256 * p;
          int b = q >> 4, vv = (q & 15) * 8;
          const float* sp = sim + b * V + vb + vv;
          bf16x8 h, l;
#pragma unroll
          for (int i = 0; i < 8; ++i) {
            int si = (int)sp[i];
            h[i] = (bf16_t)(float)(si >> 8);
            l[i] = (bf16_t)(float)(si & 255);
          }
          *(bf16x8*)&lA[b * 136 + vv]  = h;
          *(bf16x8*)&lA2[b * 136 + vv] = l;
        }
        __syncthreads();
#pragma unroll
        for (int ks2 = 0; ks2 < 4; ++ks2) {
          const int kb = ks2 * 32 + quad * 8;
          bf16x8 bfrag = *(const bf16x8*)(bp + vb + kb);
#pragma unroll
          for (int mt = 0; mt < 4; ++mt) {
            bf16x8 ah = *(const bf16x8*)&lA[(mt * 16 + lm) * 136 + kb];
            bf16x8 al = *(const bf16x8*)&lA2[(mt * 16 + lm) * 136 + kb];
            accH[mt] = __builtin_amdgcn_mfma_f32_16x16x32_bf16(ah, bfrag, accH[mt], 0, 0, 0);
            accL[mt] = __builtin_amdgcn_mfma_f32_16x16x32_bf16(al, bfrag, accL[mt], 0, 0, 0);
          }
        }
      }
      bool anyd = false;
      const int d = d0 + w * 16 + lm;
#pragma unroll
      for (int mt = 0; mt < 4; ++mt)
#pragma unroll
        for (int r = 0; r < 4; ++r) {
          int b = mt * 16 + quad * 4 + r;
          float val = 256.f * accH[mt][r] + accL[mt][r];
          float s = (val > 0.f) ? 1.f : ((val < 0.f) ? -1.f : 0.f);
          long idx = ((long)b * F + fU) * D + d;
          estOut[idx] = (bf16_t)s;
          anyd |= ((float)estIn[idx] != s);
        }
      if (__any(anyd) && lane == 0) atomicOr(&anydiff[j], 1);
      // zero next iteration's sim ping (exactly covers 2*SIMN/2 floats)
      simR[((j + 1) & 1) * SIMN + bid * 256 + t] = 0.f;
    }
    gridbar(cnt, gen);

    if (__hip_atomic_load(&anydiff[j], __ATOMIC_ACQUIRE, __HIP_MEMORY_SCOPE_AGENT) == 0) {
      done_at = j;
      break;  // uniform across the whole grid -> barrier counts stay matched
    }
  }

  const int jlast = (done_at < ITERS) ? done_at : (ITERS - 1);
  const int par = (jlast + 1) & 1;  // parity of latest est AND of zeroed sim ping
  const bf16_t* estF = par ? est1 : est0;
  float* simF = simR + par * SIMN;

  // ---------------- final projection: simF = est . Cb ---------------------
  {
    const int v0 = vtS * 64;
    const int dbase = ksS * 512;
    const bf16_t* bp = Cb + ((long)(fS * V + v0 + w * 16 + lm)) * D + dbase;

    f32x4 zero = {0.f, 0.f, 0.f, 0.f};
    f32x4 acc[4];
#pragma unroll
    for (int mt = 0; mt < 4; ++mt) acc[mt] = zero;

    for (int c = 0; c < 4; ++c) {
      const int d0c = dbase + c * 128;
      __syncthreads();
#pragma unroll
      for (int p = 0; p < 4; ++p) {
        int q = t + 256 * p;
        int b = q >> 4, dd = (q & 15) * 8;
        *(bf16x8*)&lA[b * 136 + dd] =
            *(const bf16x8*)(estF + ((long)b * F + fS) * D + d0c + dd);
      }
      __syncthreads();
#pragma unroll
      for (int ks2 = 0; ks2 < 4; ++ks2) {
        const int kb = ks2 * 32 + quad * 8;
        bf16x8 bfrag = *(const bf16x8*)(bp + c * 128 + kb);
#pragma unroll
        for (int mt = 0; mt < 4; ++mt) {
          bf16x8 afrag = *(const bf16x8*)&lA[(mt * 16 + lm) * 136 + kb];
          acc[mt] = __builtin_amdgcn_mfma_f32_16x16x32_bf16(afrag, bfrag, acc[mt], 0, 0, 0);
        }
      }
    }
    const int v = v0 + w * 16 + lm;
#pragma unroll
    for (int mt = 0; mt < 4; ++mt)
#pragma unroll
      for (int r = 0; r < 4; ++r) {
        int b = mt * 16 + quad * 4 + r;
        atomicAdd(&simF[(fS * B + b) * V + v], acc[mt][r]);
      }
  }
  gridbar(cnt, gen);

  // ---------------- argmax + count ----------------------------------------
  if (bid < B * F && t < 64) {
    int b = bid / F, f = bid % F;
    const float* row = simF + (f * B + b) * V;
    float best = -1e30f;
    int bidx = 0;
#pragma unroll
    for (int i = 0; i < V / 64; ++i) {
      int v = lane + 64 * i;  // ascending per lane; strict > keeps first max
      float x = row[v];
      if (x > best) { best = x; bidx = v; }
    }
    for (int off = 32; off; off >>= 1) {
      float ov = __shfl_down(best, off, 64);
      int oi = __shfl_down(bidx, off, 64);
      if (ov > best || (ov == best && oi < bidx)) { best = ov; bidx = oi; }
    }
    if (lane == 0) out[b * F + f] = bidx;
    if (bid == 0 && lane == 0) out[B * F] = jlast;
  }
}

// ---------------------------------------------------------------------------
extern "C" void kernel_launch(void* const* d_in, const int* in_sizes, int n_in,
                              void* d_out, int out_size, void* d_ws, size_t ws_size,
                              hipStream_t stream) {
  const float* inputs    = (const float*)d_in[0];  // (B, D)
  const float* init_est  = (const float*)d_in[1];  // (B, F, D)
  const float* codebooks = (const float*)d_in[2];  // (F, V, D)

  char* w = (char*)d_ws;
  size_t o = 0;
  auto alloc = [&](size_t bytes) -> void* {
    void* p = w + o;
    o = (o + bytes + 255) & ~(size_t)255;
    return p;
  };
  bf16_t* Cb   = (bf16_t*)alloc((size_t)F * V * D * 2);
  bf16_t* CbT  = (bf16_t*)alloc((size_t)F * D * V * 2);
  bf16_t* est0 = (bf16_t*)alloc((size_t)B * F * D * 2);
  bf16_t* est1 = (bf16_t*)alloc((size_t)B * F * D * 2);
  float* simR  = (float*)alloc((size_t)2 * SIMN * 4);
  int* anydiff = (int*)alloc(64);
  int* barst   = (int*)alloc(64);

  k_init_small<<<1024, 256, 0, stream>>>(init_est, est0, simR, anydiff, barst);
  k_init_cb<<<dim3(128, 8, 3), 256, 0, stream>>>(codebooks, Cb, CbT);
  k_fused<<<NBLK, 256, 0, stream>>>(inputs, Cb, CbT, est0, est1, simR,
                                    anydiff, barst, (int*)d_out);
}

// Round 5
// 911.107 us; speedup vs baseline: 1.7363x; 1.7363x over previous
//
#include <hip/hip_runtime.h>

#define F 3
#define V 512
#define D 8192
#define B 64
#define ITERS 10
#define NBLK 384
#define NGRP 24
#define GRPSZ (NBLK / NGRP)  // 16
#define SIMN (F * B * V)

typedef __bf16 bf16_t;
typedef __bf16 bf16x8 __attribute__((ext_vector_type(8)));
typedef __bf16 bf16x4 __attribute__((ext_vector_type(4)));
typedef float f32x4 __attribute__((ext_vector_type(4)));

// ---------------------------------------------------------------------------
// two-level grid barrier. Lines: barst[0]=gen, barst[64]=master cnt,
// barst[128 + g*64]=group cnt (all 256B apart -> no false sharing).
// Polls are RELAXED (no per-poll cache ops) + s_sleep backoff; one acquire
// fence on exit / release fence on entry for cross-XCD visibility.
// Safe: all NBLK blocks co-resident by capacity (<=32KB LDS, 124 VGPR ->
// >=2 blocks/CU; 384 blocks < 512 capacity).
// ---------------------------------------------------------------------------
__device__ inline void gridbar(int* barst) {
  __syncthreads();
  if (threadIdx.x == 0) {
    __builtin_amdgcn_fence(__ATOMIC_RELEASE, "agent");
    int* gen  = barst;
    int* mcnt = barst + 64;
    int* gcnt = barst + 128 + (blockIdx.x / GRPSZ) * 64;
    int g0 = __hip_atomic_load(gen, __ATOMIC_RELAXED, __HIP_MEMORY_SCOPE_AGENT);
    int a = __hip_atomic_fetch_add(gcnt, 1, __ATOMIC_ACQ_REL, __HIP_MEMORY_SCOPE_AGENT);
    if (a == GRPSZ - 1) {
      __hip_atomic_store(gcnt, 0, __ATOMIC_RELAXED, __HIP_MEMORY_SCOPE_AGENT);
      int m = __hip_atomic_fetch_add(mcnt, 1, __ATOMIC_ACQ_REL, __HIP_MEMORY_SCOPE_AGENT);
      if (m == NGRP - 1) {
        __hip_atomic_store(mcnt, 0, __ATOMIC_RELAXED, __HIP_MEMORY_SCOPE_AGENT);
        __hip_atomic_store(gen, g0 + 1, __ATOMIC_RELEASE, __HIP_MEMORY_SCOPE_AGENT);
      }
    }
    while (__hip_atomic_load(gen, __ATOMIC_RELAXED, __HIP_MEMORY_SCOPE_AGENT) == g0)
      __builtin_amdgcn_s_sleep(4);
    __builtin_amdgcn_fence(__ATOMIC_ACQUIRE, "agent");
  }
  __syncthreads();
}

// LDS addressing: row-stride 128 halves (256B); 16B column chunk XOR-swizzled
// by (row&7) -> conflict-free b128 reads and writes (<=2-way, free).
__device__ inline int lofs(int row, int k8) {
  return row * 128 + ((k8 ^ (row & 7)) << 3);
}

// ---------------------------------------------------------------------------
// init: est0 = bf16(init_estimates); zero sim ping-pong, flags, barrier state
// ---------------------------------------------------------------------------
__global__ void k_init_small(const float* __restrict__ ie, bf16_t* __restrict__ est0,
                             float* __restrict__ simR, int* __restrict__ anydiff,
                             int* __restrict__ barst) {
  long tid = (long)blockIdx.x * blockDim.x + threadIdx.x;
  long NT  = (long)gridDim.x * blockDim.x;
  for (long i = tid * 4; i < (long)B * F * D; i += NT * 4) {
    f32x4 x = *(const f32x4*)(ie + i);
    bf16x4 y;
    y[0] = (bf16_t)x[0]; y[1] = (bf16_t)x[1]; y[2] = (bf16_t)x[2]; y[3] = (bf16_t)x[3];
    *(bf16x4*)(est0 + i) = y;
  }
  f32x4 z = {0.f, 0.f, 0.f, 0.f};
  for (long i = tid * 4; i < (long)2 * SIMN; i += NT * 4)
    *(f32x4*)(simR + i) = z;
  if (tid < 16) anydiff[tid] = 0;
  if (tid < 2048) barst[tid] = 0;
}

// ---------------------------------------------------------------------------
// init: codebooks (fp32, read once) -> Cb bf16 [f][v][d] and CbT bf16 [f][d][v]
// ---------------------------------------------------------------------------
__global__ __launch_bounds__(256) void k_init_cb(const float* __restrict__ Csrc,
                                                 bf16_t* __restrict__ Cb,
                                                 bf16_t* __restrict__ CbT) {
  int f = blockIdx.z, vt = blockIdx.y, dt = blockIdx.x;
  __shared__ bf16_t tile[64 * 65];
  int t = threadIdx.x;
  int v0 = vt * 64, d0 = dt * 64;
#pragma unroll
  for (int p = 0; p < 16; ++p) {
    int q = t + 256 * p;
    int i = q >> 6, j = q & 63;
    bf16_t x = (bf16_t)Csrc[((long)(f * V + v0 + i)) * D + d0 + j];
    tile[i * 65 + j] = x;
    Cb[((long)(f * V + v0 + i)) * D + d0 + j] = x;
  }
  __syncthreads();
#pragma unroll
  for (int p = 0; p < 16; ++p) {
    int q = t + 256 * p;
    int jj = q >> 6, ii = q & 63;
    CbT[((long)f * D + d0 + jj) * V + v0 + ii] = tile[ii * 65 + jj];
  }
}

// ---------------------------------------------------------------------------
// fused resonator loop: 10x (sim -> bar -> upd -> bar -> uniform break),
// then final projection -> bar -> argmax + count. One launch.
// All arithmetic exact (integer values; fp32 accum < 2^24; 256*h+l split).
// ---------------------------------------------------------------------------
__global__ __launch_bounds__(256, 2) void k_fused(const float* __restrict__ inputs,
                                                  const bf16_t* __restrict__ Cb,
                                                  const bf16_t* __restrict__ CbT,
                                                  bf16_t* __restrict__ est0,
                                                  bf16_t* __restrict__ est1,
                                                  float* __restrict__ simR,
                                                  int* __restrict__ anydiff,
                                                  int* __restrict__ barst,
                                                  int* __restrict__ out) {
  __shared__ __attribute__((aligned(16))) bf16_t lds[2 * 64 * 128];  // 32 KB
  bf16_t* lA  = lds;            // sim: A tile | upd: hi plane
  bf16_t* lA2 = lds + 64 * 128; //             | upd: lo plane

  const int bid = blockIdx.x;
  const int t = threadIdx.x;
  const int lane = t & 63, w = t >> 6;
  const int lm = lane & 15, quad = lane >> 4;

  // block roles
  const int fS = bid >> 7;            // sim: f 0..2
  const int rS = bid & 127;
  const int vtS = rS >> 4;            // 0..7   -> v0 = vtS*64
  const int ksS = rS & 15;            // 0..15  -> dbase = ksS*512
  const int fU = bid >> 7;            // upd: f 0..2
  const int dtU = bid & 127;          // 0..127 -> d0 = dtU*64

  int done_at = ITERS;

  for (int j = 0; j < ITERS; ++j) {
    // ---------------- sim phase: simR[j&1] += newest . Cb -----------------
    {
      const bf16_t* est = (j & 1) ? est1 : est0;
      float* sim = simR + (j & 1) * SIMN;
      const int f1 = (fS + 1) % 3, f2 = (fS + 2) % 3;
      const int v0 = vtS * 64;
      const int dbase = ksS * 512;
      const bf16_t* bp = Cb + ((long)(fS * V + v0 + w * 16 + lm)) * D + dbase;

      f32x4 zero = {0.f, 0.f, 0.f, 0.f};
      f32x4 acc[4];
#pragma unroll
      for (int mt = 0; mt < 4; ++mt) acc[mt] = zero;

      for (int c = 0; c < 4; ++c) {
        const int d0c = dbase + c * 128;
        __syncthreads();
#pragma unroll
        for (int p = 0; p < 4; ++p) {
          int q = t + 256 * p;
          int b = q >> 4, d8 = q & 15;
          int dd = d8 * 8;
          const float* ip = inputs + (long)b * D + d0c + dd;
          f32x4 x0 = *(const f32x4*)ip;
          f32x4 x1 = *(const f32x4*)(ip + 4);
          bf16x8 e1 = *(const bf16x8*)(est + ((long)b * F + f1) * D + d0c + dd);
          bf16x8 e2 = *(const bf16x8*)(est + ((long)b * F + f2) * D + d0c + dd);
          bf16x8 o;
#pragma unroll
          for (int i = 0; i < 4; ++i) {
            o[i]     = (bf16_t)(x0[i] * (float)e1[i]     * (float)e2[i]);
            o[i + 4] = (bf16_t)(x1[i] * (float)e1[i + 4] * (float)e2[i + 4]);
          }
          *(bf16x8*)&lA[lofs(b, d8)] = o;
        }
        __syncthreads();
#pragma unroll
        for (int ks2 = 0; ks2 < 4; ++ks2) {
          const int kb = ks2 * 32 + quad * 8;
          const int k8 = ks2 * 4 + quad;
          bf16x8 bfrag = *(const bf16x8*)(bp + c * 128 + kb);
#pragma unroll
          for (int mt = 0; mt < 4; ++mt) {
            bf16x8 afrag = *(const bf16x8*)&lA[lofs(mt * 16 + lm, k8)];
            acc[mt] = __builtin_amdgcn_mfma_f32_16x16x32_bf16(afrag, bfrag, acc[mt], 0, 0, 0);
          }
        }
      }
      const int v = v0 + w * 16 + lm;
#pragma unroll
      for (int mt = 0; mt < 4; ++mt)
#pragma unroll
        for (int r = 0; r < 4; ++r) {
          int b = mt * 16 + quad * 4 + r;
          atomicAdd(&sim[(fS * B + b) * V + v], acc[mt][r]);
        }
    }
    gridbar(barst);

    // ---------------- upd phase: est' = sign(sim . CbT) -------------------
    {
      const bf16_t* estIn = (j & 1) ? est1 : est0;
      bf16_t* estOut = (j & 1) ? est0 : est1;
      const float* sim = simR + (j & 1) * SIMN + fU * (B * V);
      const int d0 = dtU * 64;
      const bf16_t* bp = CbT + ((long)fU * D + d0 + w * 16 + lm) * V;

      f32x4 zero = {0.f, 0.f, 0.f, 0.f};
      f32x4 accH[4], accL[4];
#pragma unroll
      for (int mt = 0; mt < 4; ++mt) { accH[mt] = zero; accL[mt] = zero; }

      for (int c = 0; c < 4; ++c) {
        const int vb = c * 128;
        __syncthreads();
#pragma unroll
        for (int p = 0; p < 4; ++p) {
          int q = t + 256 * p;
          int b = q >> 4, v8 = q & 15;
          const float* sp = sim + b * V + vb + v8 * 8;
          bf16x8 h, l;
#pragma unroll
          for (int i = 0; i < 8; ++i) {
            int si = (int)sp[i];
            h[i] = (bf16_t)(float)(si >> 8);
            l[i] = (bf16_t)(float)(si & 255);
          }
          *(bf16x8*)&lA[lofs(b, v8)]  = h;
          *(bf16x8*)&lA2[lofs(b, v8)] = l;
        }
        __syncthreads();
#pragma unroll
        for (int ks2 = 0; ks2 < 4; ++ks2) {
          const int kb = ks2 * 32 + quad * 8;
          const int k8 = ks2 * 4 + quad;
          bf16x8 bfrag = *(const bf16x8*)(bp + vb + kb);
#pragma unroll
          for (int mt = 0; mt < 4; ++mt) {
            bf16x8 ah = *(const bf16x8*)&lA[lofs(mt * 16 + lm, k8)];
            bf16x8 al = *(const bf16x8*)&lA2[lofs(mt * 16 + lm, k8)];
            accH[mt] = __builtin_amdgcn_mfma_f32_16x16x32_bf16(ah, bfrag, accH[mt], 0, 0, 0);
            accL[mt] = __builtin_amdgcn_mfma_f32_16x16x32_bf16(al, bfrag, accL[mt], 0, 0, 0);
          }
        }
      }
      bool anyd = false;
      const int d = d0 + w * 16 + lm;
#pragma unroll
      for (int mt = 0; mt < 4; ++mt)
#pragma unroll
        for (int r = 0; r < 4; ++r) {
          int b = mt * 16 + quad * 4 + r;
          float val = 256.f * accH[mt][r] + accL[mt][r];
          float s = (val > 0.f) ? 1.f : ((val < 0.f) ? -1.f : 0.f);
          long idx = ((long)b * F + fU) * D + d;
          estOut[idx] = (bf16_t)s;
          anyd |= ((float)estIn[idx] != s);
        }
      if (__any(anyd) && lane == 0) atomicOr(&anydiff[j], 1);
      // zero next iteration's sim ping (384*256 = 2*SIMN/2... covers SIMN)
      simR[((j + 1) & 1) * SIMN + bid * 256 + t] = 0.f;
    }
    gridbar(barst);

    if (__hip_atomic_load(&anydiff[j], __ATOMIC_ACQUIRE, __HIP_MEMORY_SCOPE_AGENT) == 0) {
      done_at = j;
      break;  // uniform across grid -> barrier counts stay matched
    }
  }

  const int jlast = (done_at < ITERS) ? done_at : (ITERS - 1);
  const int par = (jlast + 1) & 1;  // parity of latest est AND zeroed sim ping
  const bf16_t* estF = par ? est1 : est0;
  float* simF = simR + par * SIMN;

  // ---------------- final projection: simF = est . Cb ---------------------
  {
    const int v0 = vtS * 64;
    const int dbase = ksS * 512;
    const bf16_t* bp = Cb + ((long)(fS * V + v0 + w * 16 + lm)) * D + dbase;

    f32x4 zero = {0.f, 0.f, 0.f, 0.f};
    f32x4 acc[4];
#pragma unroll
    for (int mt = 0; mt < 4; ++mt) acc[mt] = zero;

    for (int c = 0; c < 4; ++c) {
      const int d0c = dbase + c * 128;
      __syncthreads();
#pragma unroll
      for (int p = 0; p < 4; ++p) {
        int q = t + 256 * p;
        int b = q >> 4, d8 = q & 15;
        *(bf16x8*)&lA[lofs(b, d8)] =
            *(const bf16x8*)(estF + ((long)b * F + fS) * D + d0c + d8 * 8);
      }
      __syncthreads();
#pragma unroll
      for (int ks2 = 0; ks2 < 4; ++ks2) {
        const int kb = ks2 * 32 + quad * 8;
        const int k8 = ks2 * 4 + quad;
        bf16x8 bfrag = *(const bf16x8*)(bp + c * 128 + kb);
#pragma unroll
        for (int mt = 0; mt < 4; ++mt) {
          bf16x8 afrag = *(const bf16x8*)&lA[lofs(mt * 16 + lm, k8)];
          acc[mt] = __builtin_amdgcn_mfma_f32_16x16x32_bf16(afrag, bfrag, acc[mt], 0, 0, 0);
        }
      }
    }
    const int v = v0 + w * 16 + lm;
#pragma unroll
    for (int mt = 0; mt < 4; ++mt)
#pragma unroll
      for (int r = 0; r < 4; ++r) {
        int b = mt * 16 + quad * 4 + r;
        atomicAdd(&simF[(fS * B + b) * V + v], acc[mt][r]);
      }
  }
  gridbar(barst);

  // ---------------- argmax + count ----------------------------------------
  if (bid < B * F && t < 64) {
    int b = bid / F, f = bid % F;
    const float* row = simF + (f * B + b) * V;
    float best = -1e30f;
    int bidx = 0;
#pragma unroll
    for (int i = 0; i < V / 64; ++i) {
      int v = lane + 64 * i;  // ascending per lane; strict > keeps first max
      float x = row[v];
      if (x > best) { best = x; bidx = v; }
    }
    for (int off = 32; off; off >>= 1) {
      float ov = __shfl_down(best, off, 64);
      int oi = __shfl_down(bidx, off, 64);
      if (ov > best || (ov == best && oi < bidx)) { best = ov; bidx = oi; }
    }
    if (lane == 0) out[b * F + f] = bidx;
    if (bid == 0 && lane == 0) out[B * F] = jlast;
  }
}

// ---------------------------------------------------------------------------
extern "C" void kernel_launch(void* const* d_in, const int* in_sizes, int n_in,
                              void* d_out, int out_size, void* d_ws, size_t ws_size,
                              hipStream_t stream) {
  const float* inputs    = (const float*)d_in[0];  // (B, D)
  const float* init_est  = (const float*)d_in[1];  // (B, F, D)
  const float* codebooks = (const float*)d_in[2];  // (F, V, D)

  char* w = (char*)d_ws;
  size_t o = 0;
  auto alloc = [&](size_t bytes) -> void* {
    void* p = w + o;
    o = (o + bytes + 255) & ~(size_t)255;
    return p;
  };
  bf16_t* Cb   = (bf16_t*)alloc((size_t)F * V * D * 2);
  bf16_t* CbT  = (bf16_t*)alloc((size_t)F * D * V * 2);
  bf16_t* est0 = (bf16_t*)alloc((size_t)B * F * D * 2);
  bf16_t* est1 = (bf16_t*)alloc((size_t)B * F * D * 2);
  float* simR  = (float*)alloc((size_t)2 * SIMN * 4);
  int* anydiff = (int*)alloc(64 * 4);
  int* barst   = (int*)alloc(2048 * 4);

  k_init_small<<<1024, 256, 0, stream>>>(init_est, est0, simR, anydiff, barst);
  k_init_cb<<<dim3(128, 8, 3), 256, 0, stream>>>(codebooks, Cb, CbT);
  k_fused<<<NBLK, 256, 0, stream>>>(inputs, Cb, CbT, est0, est1, simR,
                                    anydiff, barst, (int*)d_out);
}

// Round 6
// 788.977 us; speedup vs baseline: 2.0050x; 1.1548x over previous
//
#include <hip/hip_runtime.h>

#define F 3
#define V 512
#define D 8192
#define B 64
#define ITERS 10
#define NBLK 384
#define NGRP 24
#define GRPSZ (NBLK / NGRP)  // 16
#define SIMN (F * B * V)

typedef __bf16 bf16_t;
typedef __bf16 bf16x8 __attribute__((ext_vector_type(8)));
typedef __bf16 bf16x4 __attribute__((ext_vector_type(4)));
typedef float f32x4 __attribute__((ext_vector_type(4)));
typedef unsigned long long ull;

// ---------------------------------------------------------------------------
// device-coherent (LLC point-of-coherence) accessors — bypass L1/L2, so no
// fences (L2 writeback/invalidate) are needed anywhere in the kernel.
// ---------------------------------------------------------------------------
__device__ inline float cohLoadF(const float* p) {
  return __hip_atomic_load(p, __ATOMIC_RELAXED, __HIP_MEMORY_SCOPE_AGENT);
}
__device__ inline void cohStoreF(float* p, float v) {
  __hip_atomic_store(p, v, __ATOMIC_RELAXED, __HIP_MEMORY_SCOPE_AGENT);
}
__device__ inline ull cohLoadU8(const void* p) {
  return __hip_atomic_load((const ull*)p, __ATOMIC_RELAXED, __HIP_MEMORY_SCOPE_AGENT);
}
__device__ inline void cohStoreU8(void* p, ull v) {
  __hip_atomic_store((ull*)p, v, __ATOMIC_RELAXED, __HIP_MEMORY_SCOPE_AGENT);
}
__device__ inline bf16x8 cohLoadBf8(const bf16_t* p) {
  union { ull u[2]; bf16x8 v; } c;
  c.u[0] = cohLoadU8(p);
  c.u[1] = cohLoadU8(p + 4);
  return c.v;
}

// ---------------------------------------------------------------------------
// fence-free grid barrier: monotone relaxed counters keyed by epoch (no reset
// race), two levels (group line / master line / gen line, 256B apart).
// Ordering: __syncthreads drains vmcnt(0) per wave (coherent stores acked at
// LLC) before arrival; post-barrier reads are coherent (bypass caches).
// Safe: all 384 blocks co-resident (32KB LDS, <=168 VGPR -> >=2 blocks/CU).
// ---------------------------------------------------------------------------
__device__ inline void gridbar(int* barst, int epoch) {
  __syncthreads();
  if (threadIdx.x == 0) {
    __atomic_signal_fence(__ATOMIC_SEQ_CST);
    int* gen  = barst;
    int* mcnt = barst + 64;
    int* gcnt = barst + 128 + (blockIdx.x / GRPSZ) * 64;
    int a = __hip_atomic_fetch_add(gcnt, 1, __ATOMIC_RELAXED, __HIP_MEMORY_SCOPE_AGENT);
    if (a == epoch * GRPSZ + (GRPSZ - 1)) {
      int m = __hip_atomic_fetch_add(mcnt, 1, __ATOMIC_RELAXED, __HIP_MEMORY_SCOPE_AGENT);
      if (m == epoch * NGRP + (NGRP - 1))
        __hip_atomic_store(gen, epoch + 1, __ATOMIC_RELAXED, __HIP_MEMORY_SCOPE_AGENT);
    }
    while (__hip_atomic_load(gen, __ATOMIC_RELAXED, __HIP_MEMORY_SCOPE_AGENT) <= epoch)
      __builtin_amdgcn_s_sleep(2);
    __atomic_signal_fence(__ATOMIC_SEQ_CST);
  }
  __syncthreads();
}

// LDS addressing: row stride 128 halves; 16B chunk XOR-swizzled by row&7.
__device__ inline int lofs(int row, int k8) {
  return row * 128 + ((k8 ^ (row & 7)) << 3);
}

// ---------------------------------------------------------------------------
// init: est0 = bf16(init_estimates); zero sim ping-pong, flags, barrier state
// ---------------------------------------------------------------------------
__global__ void k_init_small(const float* __restrict__ ie, bf16_t* __restrict__ est0,
                             float* __restrict__ simR, int* __restrict__ anydiff,
                             int* __restrict__ barst) {
  long tid = (long)blockIdx.x * blockDim.x + threadIdx.x;
  long NT  = (long)gridDim.x * blockDim.x;
  for (long i = tid * 4; i < (long)B * F * D; i += NT * 4) {
    f32x4 x = *(const f32x4*)(ie + i);
    bf16x4 y;
    y[0] = (bf16_t)x[0]; y[1] = (bf16_t)x[1]; y[2] = (bf16_t)x[2]; y[3] = (bf16_t)x[3];
    *(bf16x4*)(est0 + i) = y;
  }
  f32x4 z = {0.f, 0.f, 0.f, 0.f};
  for (long i = tid * 4; i < (long)2 * SIMN; i += NT * 4)
    *(f32x4*)(simR + i) = z;
  if (tid < 16) anydiff[tid] = 0;
  if (tid < 2048) barst[tid] = 0;
}

// ---------------------------------------------------------------------------
// init: codebooks (fp32, read once) -> Cb bf16 [f][v][d] and CbT bf16 [f][d][v]
// ---------------------------------------------------------------------------
__global__ __launch_bounds__(256) void k_init_cb(const float* __restrict__ Csrc,
                                                 bf16_t* __restrict__ Cb,
                                                 bf16_t* __restrict__ CbT) {
  int f = blockIdx.z, vt = blockIdx.y, dt = blockIdx.x;
  __shared__ bf16_t tile[64 * 65];
  int t = threadIdx.x;
  int v0 = vt * 64, d0 = dt * 64;
#pragma unroll
  for (int p = 0; p < 16; ++p) {
    int q = t + 256 * p;
    int i = q >> 6, j = q & 63;
    bf16_t x = (bf16_t)Csrc[((long)(f * V + v0 + i)) * D + d0 + j];
    tile[i * 65 + j] = x;
    Cb[((long)(f * V + v0 + i)) * D + d0 + j] = x;
  }
  __syncthreads();
#pragma unroll
  for (int p = 0; p < 16; ++p) {
    int q = t + 256 * p;
    int jj = q >> 6, ii = q & 63;
    CbT[((long)f * D + d0 + jj) * V + v0 + ii] = tile[ii * 65 + jj];
  }
}

// ---------------------------------------------------------------------------
// fused resonator loop (one launch): 10x (sim -> bar -> upd -> bar -> uniform
// break), final projection -> bar -> argmax+count. Exact integer arithmetic.
// Cross-block data (est, sim, flags) flows through coherent LLC ops only;
// codebooks/inputs use normal cached loads and stay L2-hot (no fences ever).
// ---------------------------------------------------------------------------
__global__ __launch_bounds__(256, 2) void k_fused(const float* __restrict__ inputs,
                                                  const bf16_t* __restrict__ Cb,
                                                  const bf16_t* __restrict__ CbT,
                                                  bf16_t* __restrict__ est0,
                                                  bf16_t* __restrict__ est1,
                                                  float* __restrict__ simR,
                                                  int* __restrict__ anydiff,
                                                  int* __restrict__ barst,
                                                  int* __restrict__ out) {
  __shared__ __attribute__((aligned(16))) bf16_t lds[2 * 64 * 128];  // 32 KB
  bf16_t* lA  = lds;            // sim: A tile | upd: hi plane | epilogue tile
  bf16_t* lA2 = lds + 64 * 128; //             | upd: lo plane

  const int bid = blockIdx.x;
  const int t = threadIdx.x;
  const int lane = t & 63, w = t >> 6;
  const int lm = lane & 15, quad = lane >> 4;

  // block roles
  const int fS = bid >> 7;            // sim: f 0..2
  const int rS = bid & 127;
  const int vtS = rS >> 4;            // 0..7   -> v0 = vtS*64
  const int ksS = rS & 15;            // 0..15  -> dbase = ksS*512
  const int fU = bid >> 7;            // upd: f 0..2
  const int dtU = bid & 127;          // 0..127 -> d0 = dtU*64

  int done_at = ITERS;
  int epoch = 0;

  for (int j = 0; j < ITERS; ++j) {
    // ---------------- sim phase: simR[j&1] += newest . Cb -----------------
    {
      const bf16_t* est = (j & 1) ? est1 : est0;
      float* sim = simR + (j & 1) * SIMN;
      const int f1 = (fS + 1) % 3, f2 = (fS + 2) % 3;
      const int v0 = vtS * 64;
      const int dbase = ksS * 512;
      const bf16_t* bp = Cb + ((long)(fS * V + v0 + w * 16 + lm)) * D + dbase;

      f32x4 zero = {0.f, 0.f, 0.f, 0.f};
      f32x4 acc[4];
#pragma unroll
      for (int mt = 0; mt < 4; ++mt) acc[mt] = zero;

      for (int c = 0; c < 4; ++c) {
        const int d0c = dbase + c * 128;
        __syncthreads();
#pragma unroll
        for (int p = 0; p < 4; ++p) {
          int q = t + 256 * p;
          int b = q >> 4, d8 = q & 15;
          int dd = d8 * 8;
          const float* ip = inputs + (long)b * D + d0c + dd;
          f32x4 x0 = *(const f32x4*)ip;
          f32x4 x1 = *(const f32x4*)(ip + 4);
          bf16x8 e1 = cohLoadBf8(est + ((long)b * F + f1) * D + d0c + dd);
          bf16x8 e2 = cohLoadBf8(est + ((long)b * F + f2) * D + d0c + dd);
          bf16x8 o;
#pragma unroll
          for (int i = 0; i < 4; ++i) {
            o[i]     = (bf16_t)(x0[i] * (float)e1[i]     * (float)e2[i]);
            o[i + 4] = (bf16_t)(x1[i] * (float)e1[i + 4] * (float)e2[i + 4]);
          }
          *(bf16x8*)&lA[lofs(b, d8)] = o;
        }
        __syncthreads();
#pragma unroll
        for (int ks2 = 0; ks2 < 4; ++ks2) {
          const int kb = ks2 * 32 + quad * 8;
          const int k8 = ks2 * 4 + quad;
          bf16x8 bfrag = *(const bf16x8*)(bp + c * 128 + kb);  // L2-cached
#pragma unroll
          for (int mt = 0; mt < 4; ++mt) {
            bf16x8 afrag = *(const bf16x8*)&lA[lofs(mt * 16 + lm, k8)];
            acc[mt] = __builtin_amdgcn_mfma_f32_16x16x32_bf16(afrag, bfrag, acc[mt], 0, 0, 0);
          }
        }
      }
      const int v = v0 + w * 16 + lm;
#pragma unroll
      for (int mt = 0; mt < 4; ++mt)
#pragma unroll
        for (int r = 0; r < 4; ++r) {
          int b = mt * 16 + quad * 4 + r;
          atomicAdd(&sim[(fS * B + b) * V + v], acc[mt][r]);
        }
    }
    gridbar(barst, epoch); ++epoch;

    // ---------------- upd phase: est' = sign(sim . CbT) -------------------
    {
      const bf16_t* estIn = (j & 1) ? est1 : est0;
      bf16_t* estOut = (j & 1) ? est0 : est1;
      const float* sim = simR + (j & 1) * SIMN + fU * (B * V);
      const int d0 = dtU * 64;
      const bf16_t* bp = CbT + ((long)fU * D + d0 + w * 16 + lm) * V;

      f32x4 zero = {0.f, 0.f, 0.f, 0.f};
      f32x4 accH[4], accL[4];
#pragma unroll
      for (int mt = 0; mt < 4; ++mt) { accH[mt] = zero; accL[mt] = zero; }

      for (int c = 0; c < 4; ++c) {
        const int vb = c * 128;
        __syncthreads();
#pragma unroll
        for (int p = 0; p < 4; ++p) {
          int q = t + 256 * p;
          int b = q >> 4, v8 = q & 15;
          const float* sp = sim + b * V + vb + v8 * 8;
          bf16x8 h, l;
#pragma unroll
          for (int i = 0; i < 8; ++i) {
            int si = (int)cohLoadF(sp + i);
            h[i] = (bf16_t)(float)(si >> 8);   // exact: si = 256*h + l
            l[i] = (bf16_t)(float)(si & 255);
          }
          *(bf16x8*)&lA[lofs(b, v8)]  = h;
          *(bf16x8*)&lA2[lofs(b, v8)] = l;
        }
        __syncthreads();
#pragma unroll
        for (int ks2 = 0; ks2 < 4; ++ks2) {
          const int kb = ks2 * 32 + quad * 8;
          const int k8 = ks2 * 4 + quad;
          bf16x8 bfrag = *(const bf16x8*)(bp + vb + kb);  // L2-cached
#pragma unroll
          for (int mt = 0; mt < 4; ++mt) {
            bf16x8 ah = *(const bf16x8*)&lA[lofs(mt * 16 + lm, k8)];
            bf16x8 al = *(const bf16x8*)&lA2[lofs(mt * 16 + lm, k8)];
            accH[mt] = __builtin_amdgcn_mfma_f32_16x16x32_bf16(ah, bfrag, accH[mt], 0, 0, 0);
            accL[mt] = __builtin_amdgcn_mfma_f32_16x16x32_bf16(al, bfrag, accL[mt], 0, 0, 0);
          }
        }
      }
      // epilogue: sign -> LDS tile (64b x 64d, stride 72) -> packed 8B
      // coherent stores + convergence compare.
      __syncthreads();  // done reading lA/lA2 fragments
#pragma unroll
      for (int mt = 0; mt < 4; ++mt)
#pragma unroll
        for (int r = 0; r < 4; ++r) {
          int b = mt * 16 + quad * 4 + r;
          float val = 256.f * accH[mt][r] + accL[mt][r];
          float s = (val > 0.f) ? 1.f : ((val < 0.f) ? -1.f : 0.f);
          lA[b * 72 + w * 16 + lm] = (bf16_t)s;
        }
      __syncthreads();
      {
        int b2 = t >> 2, seg = t & 3;
        bool anyd = false;
        long base = ((long)b2 * F + fU) * D + d0 + seg * 16;  // element index
#pragma unroll
        for (int i = 0; i < 4; ++i) {
          ull pk = *(const ull*)&lA[b2 * 72 + seg * 16 + i * 4];
          ull old = cohLoadU8(estIn + base + i * 4);
          anyd |= (old != pk);
          cohStoreU8(estOut + base + i * 4, pk);
        }
        if (__any(anyd) && lane == 0) atomicOr(&anydiff[j], 1);
      }
      // zero next iteration's sim ping (384*256 covers SIMN=98304)
      cohStoreF(&simR[((j + 1) & 1) * SIMN + bid * 256 + t], 0.f);
    }
    gridbar(barst, epoch); ++epoch;

    if (__hip_atomic_load(&anydiff[j], __ATOMIC_RELAXED, __HIP_MEMORY_SCOPE_AGENT) == 0) {
      done_at = j;
      break;  // uniform across grid -> epochs stay matched
    }
  }

  const int jlast = (done_at < ITERS) ? done_at : (ITERS - 1);
  const int par = (jlast + 1) & 1;  // parity of latest est AND zeroed sim ping
  const bf16_t* estF = par ? est1 : est0;
  float* simF = simR + par * SIMN;

  // ---------------- final projection: simF = est . Cb ---------------------
  {
    const int v0 = vtS * 64;
    const int dbase = ksS * 512;
    const bf16_t* bp = Cb + ((long)(fS * V + v0 + w * 16 + lm)) * D + dbase;

    f32x4 zero = {0.f, 0.f, 0.f, 0.f};
    f32x4 acc[4];
#pragma unroll
    for (int mt = 0; mt < 4; ++mt) acc[mt] = zero;

    for (int c = 0; c < 4; ++c) {
      const int d0c = dbase + c * 128;
      __syncthreads();
#pragma unroll
      for (int p = 0; p < 4; ++p) {
        int q = t + 256 * p;
        int b = q >> 4, d8 = q & 15;
        *(bf16x8*)&lA[lofs(b, d8)] =
            cohLoadBf8(estF + ((long)b * F + fS) * D + d0c + d8 * 8);
      }
      __syncthreads();
#pragma unroll
      for (int ks2 = 0; ks2 < 4; ++ks2) {
        const int kb = ks2 * 32 + quad * 8;
        const int k8 = ks2 * 4 + quad;
        bf16x8 bfrag = *(const bf16x8*)(bp + c * 128 + kb);
#pragma unroll
        for (int mt = 0; mt < 4; ++mt) {
          bf16x8 afrag = *(const bf16x8*)&lA[lofs(mt * 16 + lm, k8)];
          acc[mt] = __builtin_amdgcn_mfma_f32_16x16x32_bf16(afrag, bfrag, acc[mt], 0, 0, 0);
        }
      }
    }
    const int v = v0 + w * 16 + lm;
#pragma unroll
    for (int mt = 0; mt < 4; ++mt)
#pragma unroll
      for (int r = 0; r < 4; ++r) {
        int b = mt * 16 + quad * 4 + r;
        atomicAdd(&simF[(fS * B + b) * V + v], acc[mt][r]);
      }
  }
  gridbar(barst, epoch); ++epoch;

  // ---------------- argmax + count ----------------------------------------
  if (bid < B * F && t < 64) {
    int b = bid / F, f = bid % F;
    const float* row = simF + (f * B + b) * V;
    float best = -1e30f;
    int bidx = 0;
#pragma unroll
    for (int i = 0; i < V / 64; ++i) {
      int v = lane + 64 * i;  // ascending per lane; strict > keeps first max
      float x = cohLoadF(row + v);
      if (x > best) { best = x; bidx = v; }
    }
    for (int off = 32; off; off >>= 1) {
      float ov = __shfl_down(best, off, 64);
      int oi = __shfl_down(bidx, off, 64);
      if (ov > best || (ov == best && oi < bidx)) { best = ov; bidx = oi; }
    }
    if (lane == 0) out[b * F + f] = bidx;
    if (bid == 0 && lane == 0) out[B * F] = jlast;
  }
}

// ---------------------------------------------------------------------------
extern "C" void kernel_launch(void* const* d_in, const int* in_sizes, int n_in,
                              void* d_out, int out_size, void* d_ws, size_t ws_size,
                              hipStream_t stream) {
  const float* inputs    = (const float*)d_in[0];  // (B, D)
  const float* init_est  = (const float*)d_in[1];  // (B, F, D)
  const float* codebooks = (const float*)d_in[2];  // (F, V, D)

  char* w = (char*)d_ws;
  size_t o = 0;
  auto alloc = [&](size_t bytes) -> void* {
    void* p = w + o;
    o = (o + bytes + 255) & ~(size_t)255;
    return p;
  };
  bf16_t* Cb   = (bf16_t*)alloc((size_t)F * V * D * 2);
  bf16_t* CbT  = (bf16_t*)alloc((size_t)F * D * V * 2);
  bf16_t* est0 = (bf16_t*)alloc((size_t)B * F * D * 2);
  bf16_t* est1 = (bf16_t*)alloc((size_t)B * F * D * 2);
  float* simR  = (float*)alloc((size_t)2 * SIMN * 4);
  int* anydiff = (int*)alloc(64 * 4);
  int* barst   = (int*)alloc(2048 * 4);

  k_init_small<<<1024, 256, 0, stream>>>(init_est, est0, simR, anydiff, barst);
  k_init_cb<<<dim3(128, 8, 3), 256, 0, stream>>>(codebooks, Cb, CbT);
  k_fused<<<NBLK, 256, 0, stream>>>(inputs, Cb, CbT, est0, est1, simR,
                                    anydiff, barst, (int*)d_out);
}

// Round 7
// 615.544 us; speedup vs baseline: 2.5700x; 1.2818x over previous
//
#include <hip/hip_runtime.h>

#define F 3
#define V 512
#define D 8192
#define B 64
#define ITERS 10
#define NBLK 384
#define NGRP 24
#define GRPSZ (NBLK / NGRP)  // 16
#define SIMN (F * B * V)
#define ESTN (B * F * D)

typedef __bf16 bf16_t;
typedef __bf16 bf16x8 __attribute__((ext_vector_type(8)));
typedef __bf16 bf16x4 __attribute__((ext_vector_type(4)));
typedef float f32x4 __attribute__((ext_vector_type(4)));
typedef unsigned long long ull;

// coherent (LLC write-through) store — the ONLY special op on the data path
__device__ inline void cohStoreU8(void* p, ull v) {
  __hip_atomic_store((ull*)p, v, __ATOMIC_RELAXED, __HIP_MEMORY_SCOPE_AGENT);
}

// ---------------------------------------------------------------------------
// fence-free grid barrier: monotone relaxed counters keyed by epoch, two
// levels, 256B-separated lines. __syncthreads' vmcnt(0) drain orders all
// prior LLC writes (coh stores / atomics) before the signal. Post-barrier
// reads hit virgin lines (never cached pre-write) -> always fresh.
// Safe: all 384 blocks co-resident (32KB LDS, ~96 VGPR -> >=2 blocks/CU).
// ---------------------------------------------------------------------------
__device__ inline void gridbar(int* barst, int epoch) {
  __syncthreads();
  if (threadIdx.x == 0) {
    int* gen  = barst;
    int* mcnt = barst + 64;
    int* gcnt = barst + 128 + (blockIdx.x / GRPSZ) * 64;
    int a = __hip_atomic_fetch_add(gcnt, 1, __ATOMIC_RELAXED, __HIP_MEMORY_SCOPE_AGENT);
    if (a == epoch * GRPSZ + (GRPSZ - 1)) {
      int m = __hip_atomic_fetch_add(mcnt, 1, __ATOMIC_RELAXED, __HIP_MEMORY_SCOPE_AGENT);
      if (m == epoch * NGRP + (NGRP - 1))
        __hip_atomic_store(gen, epoch + 1, __ATOMIC_RELAXED, __HIP_MEMORY_SCOPE_AGENT);
    }
    while (__hip_atomic_load(gen, __ATOMIC_RELAXED, __HIP_MEMORY_SCOPE_AGENT) <= epoch)
      __builtin_amdgcn_s_sleep(2);
  }
  __syncthreads();
}

// LDS addressing: row stride 128 halves; 16B chunk XOR-swizzled by row&7.
__device__ inline int lofs(int row, int k8) {
  return row * 128 + ((k8 ^ (row & 7)) << 3);
}

// ---------------------------------------------------------------------------
// init: est[0] = bf16(init_estimates); zero ALL per-iter sim buffers + final
// sim + flags + barrier state (no in-loop zeroing needed afterwards).
// ---------------------------------------------------------------------------
__global__ void k_init_small(const float* __restrict__ ie, bf16_t* __restrict__ est0,
                             float* __restrict__ simAll, int* __restrict__ anydiff,
                             int* __restrict__ barst) {
  long tid = (long)blockIdx.x * blockDim.x + threadIdx.x;
  long NT  = (long)gridDim.x * blockDim.x;
  for (long i = tid * 4; i < (long)ESTN; i += NT * 4) {
    f32x4 x = *(const f32x4*)(ie + i);
    bf16x4 y;
    y[0] = (bf16_t)x[0]; y[1] = (bf16_t)x[1]; y[2] = (bf16_t)x[2]; y[3] = (bf16_t)x[3];
    *(bf16x4*)(est0 + i) = y;
  }
  f32x4 z = {0.f, 0.f, 0.f, 0.f};
  for (long i = tid * 4; i < (long)(ITERS + 1) * SIMN; i += NT * 4)
    *(f32x4*)(simAll + i) = z;
  if (tid < 16) anydiff[tid] = 0;
  if (tid < 2048) barst[tid] = 0;
}

// ---------------------------------------------------------------------------
// init: codebooks (fp32, read once) -> Cb bf16 [f][v][d] and CbT bf16 [f][d][v]
// ---------------------------------------------------------------------------
__global__ __launch_bounds__(256) void k_init_cb(const float* __restrict__ Csrc,
                                                 bf16_t* __restrict__ Cb,
                                                 bf16_t* __restrict__ CbT) {
  int f = blockIdx.z, vt = blockIdx.y, dt = blockIdx.x;
  __shared__ bf16_t tile[64 * 65];
  int t = threadIdx.x;
  int v0 = vt * 64, d0 = dt * 64;
#pragma unroll
  for (int p = 0; p < 16; ++p) {
    int q = t + 256 * p;
    int i = q >> 6, j = q & 63;
    bf16_t x = (bf16_t)Csrc[((long)(f * V + v0 + i)) * D + d0 + j];
    tile[i * 65 + j] = x;
    Cb[((long)(f * V + v0 + i)) * D + d0 + j] = x;
  }
  __syncthreads();
#pragma unroll
  for (int p = 0; p < 16; ++p) {
    int q = t + 256 * p;
    int jj = q >> 6, ii = q & 63;
    CbT[((long)f * D + d0 + jj) * V + v0 + ii] = tile[ii * 65 + jj];
  }
}

// ---------------------------------------------------------------------------
// fused resonator loop, virgin-buffer edition: per-iteration est/sim buffers
// are written exactly once (est: coherent stores; sim: LLC atomics) and only
// then cached-read -> no fences, full L2 reuse, codebooks stay L2-resident.
// ---------------------------------------------------------------------------
__global__ __launch_bounds__(256, 2) void k_fused(const float* __restrict__ inputs,
                                                  const bf16_t* __restrict__ Cb,
                                                  const bf16_t* __restrict__ CbT,
                                                  bf16_t* __restrict__ estAll,
                                                  float* __restrict__ simAll,
                                                  int* __restrict__ anydiff,
                                                  int* __restrict__ barst,
                                                  int* __restrict__ out) {
  __shared__ __attribute__((aligned(16))) bf16_t lds[2 * 64 * 128];  // 32 KB
  bf16_t* lA  = lds;            // sim: A tile | upd: hi plane | epilogue tile
  bf16_t* lA2 = lds + 64 * 128; //             | upd: lo plane

  const int bid = blockIdx.x;
  const int t = threadIdx.x;
  const int lane = t & 63, w = t >> 6;
  const int lm = lane & 15, quad = lane >> 4;

  // block roles
  const int fS = bid >> 7;            // sim: f 0..2
  const int rS = bid & 127;
  const int vtS = rS >> 4;            // 0..7   -> v0 = vtS*64
  const int ksS = rS & 15;            // 0..15  -> dbase = ksS*512
  const int fU = bid >> 7;            // upd: f 0..2
  const int dtU = bid & 127;          // 0..127 -> d0 = dtU*64

  int done_at = ITERS;
  int epoch = 0;

  for (int j = 0; j < ITERS; ++j) {
    // ---------------- sim phase: sim(j) += newest(est(j)) . Cb ------------
    {
      const bf16_t* est = estAll + (long)j * ESTN;   // cached reads (L2 reuse)
      float* sim = simAll + (long)j * SIMN;
      const int f1 = (fS + 1) % 3, f2 = (fS + 2) % 3;
      const int v0 = vtS * 64;
      const int dbase = ksS * 512;
      const bf16_t* bp = Cb + ((long)(fS * V + v0 + w * 16 + lm)) * D + dbase;

      f32x4 zero = {0.f, 0.f, 0.f, 0.f};
      f32x4 acc[4];
#pragma unroll
      for (int mt = 0; mt < 4; ++mt) acc[mt] = zero;

      for (int c = 0; c < 4; ++c) {
        const int d0c = dbase + c * 128;
        __syncthreads();
#pragma unroll
        for (int p = 0; p < 4; ++p) {
          int q = t + 256 * p;
          int b = q >> 4, d8 = q & 15;
          int dd = d8 * 8;
          const float* ip = inputs + (long)b * D + d0c + dd;
          f32x4 x0 = *(const f32x4*)ip;
          f32x4 x1 = *(const f32x4*)(ip + 4);
          bf16x8 e1 = *(const bf16x8*)(est + ((long)b * F + f1) * D + d0c + dd);
          bf16x8 e2 = *(const bf16x8*)(est + ((long)b * F + f2) * D + d0c + dd);
          bf16x8 o;
#pragma unroll
          for (int i = 0; i < 4; ++i) {
            o[i]     = (bf16_t)(x0[i] * (float)e1[i]     * (float)e2[i]);
            o[i + 4] = (bf16_t)(x1[i] * (float)e1[i + 4] * (float)e2[i + 4]);
          }
          *(bf16x8*)&lA[lofs(b, d8)] = o;
        }
        __syncthreads();
#pragma unroll
        for (int ks2 = 0; ks2 < 4; ++ks2) {
          const int kb = ks2 * 32 + quad * 8;
          const int k8 = ks2 * 4 + quad;
          bf16x8 bfrag = *(const bf16x8*)(bp + c * 128 + kb);  // L2-resident
#pragma unroll
          for (int mt = 0; mt < 4; ++mt) {
            bf16x8 afrag = *(const bf16x8*)&lA[lofs(mt * 16 + lm, k8)];
            acc[mt] = __builtin_amdgcn_mfma_f32_16x16x32_bf16(afrag, bfrag, acc[mt], 0, 0, 0);
          }
        }
      }
      const int v = v0 + w * 16 + lm;
#pragma unroll
      for (int mt = 0; mt < 4; ++mt)
#pragma unroll
        for (int r = 0; r < 4; ++r) {
          int b = mt * 16 + quad * 4 + r;
          atomicAdd(&sim[(fS * B + b) * V + v], acc[mt][r]);  // LLC RMW
        }
    }
    gridbar(barst, epoch); ++epoch;

    // ---------------- upd phase: est(j+1) = sign(sim(j) . CbT) ------------
    {
      const bf16_t* estIn = estAll + (long)j * ESTN;
      bf16_t* estOut = estAll + (long)(j + 1) * ESTN;
      const float* sim = simAll + (long)j * SIMN + fU * (B * V);  // cached
      const int d0 = dtU * 64;
      const bf16_t* bp = CbT + ((long)fU * D + d0 + w * 16 + lm) * V;

      f32x4 zero = {0.f, 0.f, 0.f, 0.f};
      f32x4 accH[4], accL[4];
#pragma unroll
      for (int mt = 0; mt < 4; ++mt) { accH[mt] = zero; accL[mt] = zero; }

      for (int c = 0; c < 4; ++c) {
        const int vb = c * 128;
        __syncthreads();
#pragma unroll
        for (int p = 0; p < 4; ++p) {
          int q = t + 256 * p;
          int b = q >> 4, v8 = q & 15;
          const float* sp = sim + b * V + vb + v8 * 8;
          f32x4 s0 = *(const f32x4*)sp;
          f32x4 s1 = *(const f32x4*)(sp + 4);
          bf16x8 h, l;
#pragma unroll
          for (int i = 0; i < 4; ++i) {
            int a0 = (int)s0[i], a1 = (int)s1[i];
            h[i]     = (bf16_t)(float)(a0 >> 8);   // exact: si = 256*h + l
            l[i]     = (bf16_t)(float)(a0 & 255);
            h[i + 4] = (bf16_t)(float)(a1 >> 8);
            l[i + 4] = (bf16_t)(float)(a1 & 255);
          }
          *(bf16x8*)&lA[lofs(b, v8)]  = h;
          *(bf16x8*)&lA2[lofs(b, v8)] = l;
        }
        __syncthreads();
#pragma unroll
        for (int ks2 = 0; ks2 < 4; ++ks2) {
          const int kb = ks2 * 32 + quad * 8;
          const int k8 = ks2 * 4 + quad;
          bf16x8 bfrag = *(const bf16x8*)(bp + vb + kb);  // L2-resident
#pragma unroll
          for (int mt = 0; mt < 4; ++mt) {
            bf16x8 ah = *(const bf16x8*)&lA[lofs(mt * 16 + lm, k8)];
            bf16x8 al = *(const bf16x8*)&lA2[lofs(mt * 16 + lm, k8)];
            accH[mt] = __builtin_amdgcn_mfma_f32_16x16x32_bf16(ah, bfrag, accH[mt], 0, 0, 0);
            accL[mt] = __builtin_amdgcn_mfma_f32_16x16x32_bf16(al, bfrag, accL[mt], 0, 0, 0);
          }
        }
      }
      // epilogue: sign -> LDS repack -> coherent 8B stores + convergence cmp
      __syncthreads();
#pragma unroll
      for (int mt = 0; mt < 4; ++mt)
#pragma unroll
        for (int r = 0; r < 4; ++r) {
          int b = mt * 16 + quad * 4 + r;
          float val = 256.f * accH[mt][r] + accL[mt][r];
          float s = (val > 0.f) ? 1.f : ((val < 0.f) ? -1.f : 0.f);
          lA[b * 72 + w * 16 + lm] = (bf16_t)s;
        }
      __syncthreads();
      {
        int b2 = t >> 2, seg = t & 3;
        bool anyd = false;
        long base = ((long)b2 * F + fU) * D + d0 + seg * 16;
#pragma unroll
        for (int i = 0; i < 4; ++i) {
          ull pk = *(const ull*)&lA[b2 * 72 + seg * 16 + i * 4];
          ull old = *(const ull*)(estIn + base + i * 4);  // cached, clean
          anyd |= (old != pk);
          cohStoreU8(estOut + base + i * 4, pk);          // write-through LLC
        }
        if (__any(anyd) && lane == 0) atomicOr(&anydiff[j], 1);
      }
    }
    gridbar(barst, epoch); ++epoch;

    if (__hip_atomic_load(&anydiff[j], __ATOMIC_RELAXED, __HIP_MEMORY_SCOPE_AGENT) == 0) {
      done_at = j;
      break;  // uniform across grid -> epochs stay matched
    }
  }

  const int jlast = (done_at < ITERS) ? done_at : (ITERS - 1);
  const bf16_t* estF = estAll + (long)(jlast + 1) * ESTN;  // virgin reads
  float* simF = simAll + (long)ITERS * SIMN;               // virgin buffer

  // ---------------- final projection: simF = estF . Cb --------------------
  {
    const int v0 = vtS * 64;
    const int dbase = ksS * 512;
    const bf16_t* bp = Cb + ((long)(fS * V + v0 + w * 16 + lm)) * D + dbase;

    f32x4 zero = {0.f, 0.f, 0.f, 0.f};
    f32x4 acc[4];
#pragma unroll
    for (int mt = 0; mt < 4; ++mt) acc[mt] = zero;

    for (int c = 0; c < 4; ++c) {
      const int d0c = dbase + c * 128;
      __syncthreads();
#pragma unroll
      for (int p = 0; p < 4; ++p) {
        int q = t + 256 * p;
        int b = q >> 4, d8 = q & 15;
        *(bf16x8*)&lA[lofs(b, d8)] =
            *(const bf16x8*)(estF + ((long)b * F + fS) * D + d0c + d8 * 8);
      }
      __syncthreads();
#pragma unroll
      for (int ks2 = 0; ks2 < 4; ++ks2) {
        const int kb = ks2 * 32 + quad * 8;
        const int k8 = ks2 * 4 + quad;
        bf16x8 bfrag = *(const bf16x8*)(bp + c * 128 + kb);
#pragma unroll
        for (int mt = 0; mt < 4; ++mt) {
          bf16x8 afrag = *(const bf16x8*)&lA[lofs(mt * 16 + lm, k8)];
          acc[mt] = __builtin_amdgcn_mfma_f32_16x16x32_bf16(afrag, bfrag, acc[mt], 0, 0, 0);
        }
      }
    }
    const int v = v0 + w * 16 + lm;
#pragma unroll
    for (int mt = 0; mt < 4; ++mt)
#pragma unroll
      for (int r = 0; r < 4; ++r) {
        int b = mt * 16 + quad * 4 + r;
        atomicAdd(&simF[(fS * B + b) * V + v], acc[mt][r]);
      }
  }
  gridbar(barst, epoch); ++epoch;

  // ---------------- argmax + count ----------------------------------------
  if (bid < B * F && t < 64) {
    int b = bid / F, f = bid % F;
    const float* row = simF + (f * B + b) * V;  // virgin cached reads
    float best = -1e30f;
    int bidx = 0;
#pragma unroll
    for (int i = 0; i < V / 64; ++i) {
      int v = lane + 64 * i;  // ascending per lane; strict > keeps first max
      float x = row[v];
      if (x > best) { best = x; bidx = v; }
    }
    for (int off = 32; off; off >>= 1) {
      float ov = __shfl_down(best, off, 64);
      int oi = __shfl_down(bidx, off, 64);
      if (ov > best || (ov == best && oi < bidx)) { best = ov; bidx = oi; }
    }
    if (lane == 0) out[b * F + f] = bidx;
    if (bid == 0 && lane == 0) out[B * F] = jlast;
  }
}

// ---------------------------------------------------------------------------
extern "C" void kernel_launch(void* const* d_in, const int* in_sizes, int n_in,
                              void* d_out, int out_size, void* d_ws, size_t ws_size,
                              hipStream_t stream) {
  const float* inputs    = (const float*)d_in[0];  // (B, D)
  const float* init_est  = (const float*)d_in[1];  // (B, F, D)
  const float* codebooks = (const float*)d_in[2];  // (F, V, D)

  char* w = (char*)d_ws;
  size_t o = 0;
  auto alloc = [&](size_t bytes) -> void* {
    void* p = w + o;
    o = (o + bytes + 255) & ~(size_t)255;
    return p;
  };
  bf16_t* Cb     = (bf16_t*)alloc((size_t)F * V * D * 2);             // 25.2 MB
  bf16_t* CbT    = (bf16_t*)alloc((size_t)F * D * V * 2);             // 25.2 MB
  bf16_t* estAll = (bf16_t*)alloc((size_t)(ITERS + 1) * ESTN * 2);    // 34.6 MB
  float* simAll  = (float*)alloc((size_t)(ITERS + 1) * SIMN * 4);     // 4.3 MB
  int* anydiff   = (int*)alloc(64 * 4);
  int* barst     = (int*)alloc(2048 * 4);

  k_init_small<<<1024, 256, 0, stream>>>(init_est, estAll, simAll, anydiff, barst);
  k_init_cb<<<dim3(128, 8, 3), 256, 0, stream>>>(codebooks, Cb, CbT);
  k_fused<<<NBLK, 256, 0, stream>>>(inputs, Cb, CbT, estAll, simAll,
                                    anydiff, barst, (int*)d_out);
}